// Round 6
// baseline (457.843 us; speedup 1.0000x reference)
//
#include <hip/hip_runtime.h>
#include <hip/hip_bf16.h>
#include <stdint.h>

#define D_DIM 2048
#define N_STEPS 16384
#define B_BLK 1024
#define N_BLK (N_STEPS / B_BLK)       // 16
#define T_P (B_BLK / 128)             // 8 tiles per block dim
#define N_TILE (T_P * (T_P + 1) / 2)  // 36 lower tiles per block
#define ETA 0.01f
#define NWG 256
#define FLAG_STRIDE 16  // ints -> 64B per flag line

typedef __attribute__((ext_vector_type(8))) short short8_t;
typedef __attribute__((ext_vector_type(4))) float floatx4;

__device__ __forceinline__ short f2bf(float f) {
  __hip_bfloat16 h = __float2bfloat16(f);
  return __builtin_bit_cast(short, h);
}
__device__ __forceinline__ float bf2f(uint32_t bits) {
  return __builtin_bit_cast(float, bits << 16);
}

// Write-through store (relaxed agent atomic -> global_store sc0 sc1, no cache
// flush). Visible at MALL once vmcnt retires; __syncthreads drains vmcnt.
__device__ __forceinline__ void store_wt(float* p, float v) {
  __hip_atomic_store(p, v, __ATOMIC_RELAXED, __HIP_MEMORY_SCOPE_AGENT);
}

// Async global->LDS, 16B per lane (lane-linear LDS dest).
__device__ __forceinline__ void gl_lds16(const short* g, short* l) {
  __builtin_amdgcn_global_load_lds(
      (const __attribute__((address_space(1))) void*)g,
      (__attribute__((address_space(3))) void*)l, 16, 0, 0);
}

// ---------------------------------------------------------------------------
// Phase 0: cast xs (fp32) -> xb (bf16), one pass.
// ---------------------------------------------------------------------------
__global__ __launch_bounds__(256) void cast_kernel(const float* __restrict__ xs,
                                                   short* __restrict__ xb) {
  size_t i = (size_t)blockIdx.x * 256 + threadIdx.x;
  float4 a = ((const float4*)xs)[i * 2];
  float4 b = ((const float4*)xs)[i * 2 + 1];
  short8_t v;
  v[0] = f2bf(a.x); v[1] = f2bf(a.y); v[2] = f2bf(a.z); v[3] = f2bf(a.w);
  v[4] = f2bf(b.x); v[5] = f2bf(b.y); v[6] = f2bf(b.z); v[7] = f2bf(b.w);
  *(short8_t*)(xb + i * 8) = v;
}

// ---------------------------------------------------------------------------
// Phase 1: block-local Gram tiles. R6: TWO launches of 288 WGs (8 blocks
// each). XCD x (= i&7 dispatch heuristic) gets all 36 tiles of ONE block ->
// instantaneous per-XCD panel working set = 4 MB = its L2 capacity. R5's
// single 576-WG launch put 2 blocks (8 MB) per XCD -> thrashed.
// ---------------------------------------------------------------------------
__global__ __launch_bounds__(256) void gram_kernel(const short* __restrict__ xb,
                                                   short* __restrict__ G,
                                                   int b_base) {
  int i = blockIdx.x;
  int x = i & 7;       // XCD slot
  int t = i >> 3;      // tile 0..35
  int b = b_base + x;  // one block per XCD per launch
  int ti = 0;
  while ((ti + 1) * (ti + 2) / 2 <= t) ti++;
  int tj = t - ti * (ti + 1) / 2;

  __shared__ short As[128 * 64];
  __shared__ short Bs[128 * 64];

  int tid = threadIdx.x;
  int lane = tid & 63;
  int w = tid >> 6;
  int wm = w >> 1, wn = w & 1;
  int quad = lane >> 4, rr = lane & 15;

  floatx4 acc[4][4];
#pragma unroll
  for (int ii = 0; ii < 4; ii++)
#pragma unroll
    for (int jj = 0; jj < 4; jj++)
#pragma unroll
      for (int r = 0; r < 4; r++) acc[ii][jj][r] = 0.f;

  const short* Arow = xb + (size_t)(b * B_BLK + ti * 128) * D_DIM;
  const short* Brow = xb + (size_t)(b * B_BLK + tj * 128) * D_DIM;
  bool diag = (ti == tj);

  for (int kk = 0; kk < D_DIM; kk += 64) {
#pragma unroll
    for (int tch = 0; tch < 4; tch++) {
      int chunk = tch * 256 + tid;  // 1024 x 16B chunks = 128x64 bf16
      int row = chunk >> 3, slot = chunk & 7;
      int cc = slot ^ (row & 7);  // swizzle
      gl_lds16(Arow + (size_t)row * D_DIM + kk + cc * 8, &As[chunk * 8]);
      if (!diag)
        gl_lds16(Brow + (size_t)row * D_DIM + kk + cc * 8, &Bs[chunk * 8]);
    }
    __syncthreads();  // drains vmcnt -> LDS staging complete

    const short* Bsrc = diag ? As : Bs;
#pragma unroll
    for (int ks = 0; ks < 2; ks++) {  // k-offsets 0, 32
      short8_t af[4], bfr[4];
#pragma unroll
      for (int mt = 0; mt < 4; mt++) {
        int r = wm * 64 + mt * 16 + rr;
        int slot = (ks * 4 + quad) ^ (r & 7);
        af[mt] = *(const short8_t*)(&As[r * 64 + slot * 8]);
      }
#pragma unroll
      for (int nt = 0; nt < 4; nt++) {
        int r = wn * 64 + nt * 16 + rr;
        int slot = (ks * 4 + quad) ^ (r & 7);
        bfr[nt] = *(const short8_t*)(&Bsrc[r * 64 + slot * 8]);
      }
#pragma unroll
      for (int mt = 0; mt < 4; mt++)
#pragma unroll
        for (int nt = 0; nt < 4; nt++)
          acc[mt][nt] = __builtin_amdgcn_mfma_f32_16x16x32_bf16(
              af[mt], bfr[nt], acc[mt][nt], 0, 0, 0);
    }
    __syncthreads();
  }

  // C/D layout: col=lane&15, row=(lane>>4)*4+reg  [verified m89/m91]
  size_t gbase = ((size_t)(b * N_TILE + t)) * (128 * 128);
  int col0 = lane & 15;
  int row0 = (lane >> 4) * 4;
#pragma unroll
  for (int mt = 0; mt < 4; mt++)
#pragma unroll
    for (int nt = 0; nt < 4; nt++)
#pragma unroll
      for (int r = 0; r < 4; r++) {
        int row = wm * 64 + mt * 16 + row0 + r;
        int col = wn * 64 + nt * 16 + col0;
        G[gbase + (size_t)row * 128 + col] = f2bf(acc[mt][nt][r]);
      }
}

// ---------------------------------------------------------------------------
// Flush-free grid barrier (relaxed agent atomics only; see R3 notes).
// ---------------------------------------------------------------------------
__device__ __forceinline__ void grid_barrier(int* flags, int* release, int gen,
                                             int wg, int tid) {
  __syncthreads();
  if (wg == 0) {
    if (tid > 0) {
      int guard = 0;
      while (__hip_atomic_load(&flags[tid * FLAG_STRIDE], __ATOMIC_RELAXED,
                               __HIP_MEMORY_SCOPE_AGENT) < gen &&
             guard < (1 << 20)) {
        guard++;
        __builtin_amdgcn_s_sleep(1);
      }
    }
    __syncthreads();
    if (tid == 0)
      __hip_atomic_store(release, gen, __ATOMIC_RELAXED,
                         __HIP_MEMORY_SCOPE_AGENT);
  } else {
    if (tid == 0) {
      __hip_atomic_store(&flags[wg * FLAG_STRIDE], gen, __ATOMIC_RELAXED,
                         __HIP_MEMORY_SCOPE_AGENT);
      int guard = 0;
      while (__hip_atomic_load(release, __ATOMIC_RELAXED,
                               __HIP_MEMORY_SCOPE_AGENT) < gen &&
             guard < (1 << 20)) {
        guard++;
        __builtin_amdgcn_s_sleep(1);
      }
    }
  }
  asm volatile("" ::: "memory");
  __syncthreads();
}

__device__ __forceinline__ float wave_reduce(float s) {
  for (int off = 32; off; off >>= 1) s += __shfl_xor(s, off, 64);
  return s;
}

// ---------------------------------------------------------------------------
// Phase 2: sequential over blocks, 3 flush-free barriers per block.
// (frozen from R4/R5)
// ---------------------------------------------------------------------------
__global__ __launch_bounds__(256, 1) void solve_kernel(
    const short* __restrict__ xb, const short* __restrict__ G,
    float* __restrict__ theta_arr, float* __restrict__ c0_arr,
    float* __restrict__ c1_arr, int* flags, int* release) {
  int tid = threadIdx.x;
  int wg = blockIdx.x;
  int lane = tid & 63;
  int wid = tid >> 6;
  int gw = wg * 4 + wid;  // 0..1023: one wave per step-row
  int gen = 0;

  __shared__ float c1s[B_BLK];      // 4 KB
  __shared__ float redc[4][4][8];   // wave x d-octet x elem

  for (int b = 0; b < N_BLK; b++) {
    const float* theta = theta_arr + (size_t)b * D_DIM;  // rotated
    float* c0 = c0_arr + (size_t)b * B_BLK;
    float* c1 = c1_arr + (size_t)b * B_BLK;
    float p_k;

    // ---- Phase A: p_k = <x_gw, theta_b> (registers); c0 = f(p)
    {
      const short* xr = xb + (size_t)(b * B_BLK + gw) * D_DIM;
      float s = 0.f;
#pragma unroll
      for (int i = 0; i < 4; i++) {
        int idx = (i * 64 + lane) * 8;
        short8_t xv = *(const short8_t*)(xr + idx);
        float4 t0 = *(const float4*)(theta + idx);
        float4 t1 = *(const float4*)(theta + idx + 4);
        s += bf2f((uint16_t)xv[0]) * t0.x + bf2f((uint16_t)xv[1]) * t0.y +
             bf2f((uint16_t)xv[2]) * t0.z + bf2f((uint16_t)xv[3]) * t0.w +
             bf2f((uint16_t)xv[4]) * t1.x + bf2f((uint16_t)xv[5]) * t1.y +
             bf2f((uint16_t)xv[6]) * t1.z + bf2f((uint16_t)xv[7]) * t1.w;
      }
      s = wave_reduce(s);
      p_k = s;
      if (lane == 0) store_wt(&c0[gw], ETA / (1.f + __expf(s)));
    }
    grid_barrier(flags, release, ++gen, wg, tid);

    // ---- Phase S: c1[k] = f(p_k + tril(G_b)[k,:] . c0)
    {
      int ti = gw >> 7, kr = gw & 127;
      float s = 0.f;
      for (int tj = 0; tj <= ti; tj++) {
        size_t base =
            ((size_t)(b * N_TILE + ti * (ti + 1) / 2 + tj)) * (128 * 128) +
            (size_t)kr * 128;
        uint32_t gv = *(const uint32_t*)(G + base + lane * 2);
        float2 cv = *(const float2*)(c0 + tj * 128 + lane * 2);
        int jc = lane * 2;
        int lim = (tj == ti) ? kr : 128;
        if (jc < lim) s += bf2f(gv & 0xffffu) * cv.x;
        if (jc + 1 < lim) s += bf2f(gv >> 16) * cv.y;
      }
      s = wave_reduce(s);
      if (lane == 0) store_wt(&c1[gw], ETA / (1.f + __expf(p_k + s)));
    }
    grid_barrier(flags, release, ++gen, wg, tid);

    // ---- Phase C: theta_{b+1}[d] = theta_b[d] + sum_k c1[k] xb[k][d]
    // 64 active WGs; WG wg owns d-slice [wg*32, wg*32+32) = one 64B line per
    // row -> coalesced, zero over-fetch, single-writer.
    if (wg < 64) {
#pragma unroll
      for (int i = 0; i < 4; i++) c1s[i * 256 + tid] = c1[i * 256 + tid];
      __syncthreads();
      int d0 = wg * 32;
      const short* xp =
          xb + (size_t)(b * B_BLK) * D_DIM + d0 + (lane & 3) * 8;
      float a8[8] = {0.f, 0.f, 0.f, 0.f, 0.f, 0.f, 0.f, 0.f};
      int rbase = wid * 256 + (lane >> 2);
      for (int i = 0; i < 16; i++) {
        int row = rbase + i * 16;
        short8_t xv = *(const short8_t*)(xp + (size_t)row * D_DIM);
        float c = c1s[row];
#pragma unroll
        for (int jj = 0; jj < 8; jj++) a8[jj] += c * bf2f((uint16_t)xv[jj]);
      }
      // reduce across the 16 lanes sharing (lane&3)
#pragma unroll
      for (int off = 4; off < 64; off <<= 1)
#pragma unroll
        for (int jj = 0; jj < 8; jj++) a8[jj] += __shfl_xor(a8[jj], off, 64);
      if (lane < 4) {
#pragma unroll
        for (int jj = 0; jj < 8; jj++) redc[wid][lane][jj] = a8[jj];
      }
      __syncthreads();
      if (tid < 32) {
        int oct = tid >> 3, e = tid & 7;
        float tot = redc[0][oct][e] + redc[1][oct][e] + redc[2][oct][e] +
                    redc[3][oct][e];
        store_wt(&theta_arr[(size_t)(b + 1) * D_DIM + d0 + tid],
                 theta[d0 + tid] + tot);
      }
    }
    if (b < N_BLK - 1) grid_barrier(flags, release, ++gen, wg, tid);
  }
}

// ---------------------------------------------------------------------------
extern "C" void kernel_launch(void* const* d_in, const int* in_sizes, int n_in,
                              void* d_out, int out_size, void* d_ws,
                              size_t ws_size, hipStream_t stream) {
  const float* theta_in = (const float*)d_in[0];  // (2048,)
  const float* xs = (const float*)d_in[1];        // (16384, 2048) fp32

  char* ws = (char*)d_ws;
  const size_t XB_BYTES = (size_t)N_STEPS * D_DIM * sizeof(short);  // 64MB
  const size_t G_BYTES = (size_t)N_BLK * N_TILE * 128 * 128 * sizeof(short);
  short* xb = (short*)ws;
  short* G = (short*)(ws + XB_BYTES);
  float* theta_arr = (float*)(ws + XB_BYTES + G_BYTES);  // (N_BLK+1) x 2048
  float* c0_arr = theta_arr + (size_t)(N_BLK + 1) * D_DIM;
  float* c1_arr = c0_arr + (size_t)N_BLK * B_BLK;
  int* flags = (int*)(c1_arr + (size_t)N_BLK * B_BLK);
  int* release = flags + NWG * FLAG_STRIDE;

  hipMemsetAsync(flags, 0, (NWG * FLAG_STRIDE + 16) * sizeof(int), stream);
  hipMemcpyAsync(theta_arr, theta_in, D_DIM * sizeof(float),
                 hipMemcpyDeviceToDevice, stream);

  cast_kernel<<<(N_STEPS * D_DIM / 8) / 256, 256, 0, stream>>>(xs, xb);
  gram_kernel<<<8 * N_TILE, 256, 0, stream>>>(xb, G, 0);  // blocks 0..7
  gram_kernel<<<8 * N_TILE, 256, 0, stream>>>(xb, G, 8);  // blocks 8..15
  solve_kernel<<<NWG, 256, 0, stream>>>(xb, G, theta_arr, c0_arr, c1_arr,
                                        flags, release);

  hipMemcpyAsync(d_out, theta_arr + (size_t)N_BLK * D_DIM,
                 D_DIM * sizeof(float), hipMemcpyDeviceToDevice, stream);
}

// Round 7
// 453.860 us; speedup vs baseline: 1.0088x; 1.0088x over previous
//
#include <hip/hip_runtime.h>
#include <hip/hip_bf16.h>
#include <stdint.h>

#define D_DIM 2048
#define N_STEPS 16384
#define B_BLK 1024
#define N_BLK (N_STEPS / B_BLK)       // 16
#define T_P (B_BLK / 128)             // 8 tiles per block dim
#define N_TILE (T_P * (T_P + 1) / 2)  // 36 lower tiles per block
#define ETA 0.01f
#define NWG 256
#define FLAG_STRIDE 16  // ints -> 64B per flag line

typedef __attribute__((ext_vector_type(8))) short short8_t;
typedef __attribute__((ext_vector_type(4))) float floatx4;

__device__ __forceinline__ short f2bf(float f) {
  __hip_bfloat16 h = __float2bfloat16(f);
  return __builtin_bit_cast(short, h);
}
__device__ __forceinline__ float bf2f(uint32_t bits) {
  return __builtin_bit_cast(float, bits << 16);
}

// Write-through store (relaxed agent atomic -> global_store sc0 sc1, no cache
// flush). Visible at MALL once vmcnt retires; __syncthreads drains vmcnt.
__device__ __forceinline__ void store_wt(float* p, float v) {
  __hip_atomic_store(p, v, __ATOMIC_RELAXED, __HIP_MEMORY_SCOPE_AGENT);
}

// Async global->LDS, 16B per lane (lane-linear LDS dest).
__device__ __forceinline__ void gl_lds16(const short* g, short* l) {
  __builtin_amdgcn_global_load_lds(
      (const __attribute__((address_space(1))) void*)g,
      (__attribute__((address_space(3))) void*)l, 16, 0, 0);
}

// ---------------------------------------------------------------------------
// Phase 0: cast xs (fp32) -> xb (bf16), one pass.
// ---------------------------------------------------------------------------
__global__ __launch_bounds__(256) void cast_kernel(const float* __restrict__ xs,
                                                   short* __restrict__ xb) {
  size_t i = (size_t)blockIdx.x * 256 + threadIdx.x;
  float4 a = ((const float4*)xs)[i * 2];
  float4 b = ((const float4*)xs)[i * 2 + 1];
  short8_t v;
  v[0] = f2bf(a.x); v[1] = f2bf(a.y); v[2] = f2bf(a.z); v[3] = f2bf(a.w);
  v[4] = f2bf(b.x); v[5] = f2bf(b.y); v[6] = f2bf(b.z); v[7] = f2bf(b.w);
  *(short8_t*)(xb + i * 8) = v;
}

// ---------------------------------------------------------------------------
// Phase 1: block-local Gram tiles. R7: DOUBLE-BUFFERED pipelined staging.
// Evidence: R4 (CU-internal) neutral, R5 (XCD locality) small, R6 (L2
// capacity) nil -> gram is latency-serialized per k-iter (stage -> vmcnt(0)
// drain -> compute exposes a full ~500cy MALL RT every iter at 2.25 WGs/CU).
// Fix: issue stage(it+1) into buf^1 BEFORE compute(it); next barrier's
// implicit vmcnt(0) only pays the residual. 1 barrier/iter instead of 2.
// Single 576-WG launch, R5 %8 XCD mapping (best known config).
// ---------------------------------------------------------------------------
__global__ __launch_bounds__(256) void gram_kernel(const short* __restrict__ xb,
                                                   short* __restrict__ G) {
  int i = blockIdx.x;
  int x = i & 7, j = i >> 3;  // x: XCD slot, j: 0..71
  int b = (j < 36) ? x : x + 8;
  int t = (j < 36) ? j : j - 36;
  int ti = 0;
  while ((ti + 1) * (ti + 2) / 2 <= t) ti++;
  int tj = t - ti * (ti + 1) / 2;

  __shared__ short As[2][128 * 64];  // 2 x 16 KB
  __shared__ short Bs[2][128 * 64];  // 2 x 16 KB  (total 64 KB -> 2 WGs/CU)

  int tid = threadIdx.x;
  int lane = tid & 63;
  int w = tid >> 6;
  int wm = w >> 1, wn = w & 1;
  int quad = lane >> 4, rr = lane & 15;

  floatx4 acc[4][4];
#pragma unroll
  for (int ii = 0; ii < 4; ii++)
#pragma unroll
    for (int jj = 0; jj < 4; jj++)
#pragma unroll
      for (int r = 0; r < 4; r++) acc[ii][jj][r] = 0.f;

  const short* Arow = xb + (size_t)(b * B_BLK + ti * 128) * D_DIM;
  const short* Brow = xb + (size_t)(b * B_BLK + tj * 128) * D_DIM;
  bool diag = (ti == tj);

  // stage one 128x64 A (and B) panel-slice into buffer `buf`
  auto stage = [&](int buf, int kk) {
#pragma unroll
    for (int tch = 0; tch < 4; tch++) {
      int chunk = tch * 256 + tid;  // 1024 x 16B chunks = 128x64 bf16
      int row = chunk >> 3, slot = chunk & 7;
      int cc = slot ^ (row & 7);  // XOR column swizzle
      gl_lds16(Arow + (size_t)row * D_DIM + kk + cc * 8, &As[buf][chunk * 8]);
      if (!diag)
        gl_lds16(Brow + (size_t)row * D_DIM + kk + cc * 8, &Bs[buf][chunk * 8]);
    }
  };

  stage(0, 0);
  const int NIT = D_DIM / 64;  // 32
  for (int it = 0; it < NIT; it++) {
    __syncthreads();  // implicit vmcnt(0): stage(it) complete; prev compute's
                      // ds_reads already drained by MFMA consumption
    int cur = it & 1;
    if (it + 1 < NIT) stage(cur ^ 1, (it + 1) * 64);  // flies during compute

    const short(*Asrc)[128 * 64] = &As[cur];
    const short* Bsrc = diag ? As[cur] : Bs[cur];
#pragma unroll
    for (int ks = 0; ks < 2; ks++) {  // k-offsets 0, 32
      short8_t af[4], bfr[4];
#pragma unroll
      for (int mt = 0; mt < 4; mt++) {
        int r = wm * 64 + mt * 16 + rr;
        int slot = (ks * 4 + quad) ^ (r & 7);
        af[mt] = *(const short8_t*)(&(*Asrc)[r * 64 + slot * 8]);
      }
#pragma unroll
      for (int nt = 0; nt < 4; nt++) {
        int r = wn * 64 + nt * 16 + rr;
        int slot = (ks * 4 + quad) ^ (r & 7);
        bfr[nt] = *(const short8_t*)(&Bsrc[r * 64 + slot * 8]);
      }
#pragma unroll
      for (int mt = 0; mt < 4; mt++)
#pragma unroll
        for (int nt = 0; nt < 4; nt++)
          acc[mt][nt] = __builtin_amdgcn_mfma_f32_16x16x32_bf16(
              af[mt], bfr[nt], acc[mt][nt], 0, 0, 0);
    }
  }

  // C/D layout: col=lane&15, row=(lane>>4)*4+reg  [verified m89/m91]
  size_t gbase = ((size_t)(b * N_TILE + t)) * (128 * 128);
  int col0 = lane & 15;
  int row0 = (lane >> 4) * 4;
#pragma unroll
  for (int mt = 0; mt < 4; mt++)
#pragma unroll
    for (int nt = 0; nt < 4; nt++)
#pragma unroll
      for (int r = 0; r < 4; r++) {
        int row = wm * 64 + mt * 16 + row0 + r;
        int col = wn * 64 + nt * 16 + col0;
        G[gbase + (size_t)row * 128 + col] = f2bf(acc[mt][nt][r]);
      }
}

// ---------------------------------------------------------------------------
// Flush-free grid barrier (relaxed agent atomics only; see R3 notes).
// ---------------------------------------------------------------------------
__device__ __forceinline__ void grid_barrier(int* flags, int* release, int gen,
                                             int wg, int tid) {
  __syncthreads();
  if (wg == 0) {
    if (tid > 0) {
      int guard = 0;
      while (__hip_atomic_load(&flags[tid * FLAG_STRIDE], __ATOMIC_RELAXED,
                               __HIP_MEMORY_SCOPE_AGENT) < gen &&
             guard < (1 << 20)) {
        guard++;
        __builtin_amdgcn_s_sleep(1);
      }
    }
    __syncthreads();
    if (tid == 0)
      __hip_atomic_store(release, gen, __ATOMIC_RELAXED,
                         __HIP_MEMORY_SCOPE_AGENT);
  } else {
    if (tid == 0) {
      __hip_atomic_store(&flags[wg * FLAG_STRIDE], gen, __ATOMIC_RELAXED,
                         __HIP_MEMORY_SCOPE_AGENT);
      int guard = 0;
      while (__hip_atomic_load(release, __ATOMIC_RELAXED,
                               __HIP_MEMORY_SCOPE_AGENT) < gen &&
             guard < (1 << 20)) {
        guard++;
        __builtin_amdgcn_s_sleep(1);
      }
    }
  }
  asm volatile("" ::: "memory");
  __syncthreads();
}

__device__ __forceinline__ float wave_reduce(float s) {
  for (int off = 32; off; off >>= 1) s += __shfl_xor(s, off, 64);
  return s;
}

// ---------------------------------------------------------------------------
// Phase 2: sequential over blocks, 3 flush-free barriers per block.
// (frozen from R4/R5/R6)
// ---------------------------------------------------------------------------
__global__ __launch_bounds__(256, 1) void solve_kernel(
    const short* __restrict__ xb, const short* __restrict__ G,
    float* __restrict__ theta_arr, float* __restrict__ c0_arr,
    float* __restrict__ c1_arr, int* flags, int* release) {
  int tid = threadIdx.x;
  int wg = blockIdx.x;
  int lane = tid & 63;
  int wid = tid >> 6;
  int gw = wg * 4 + wid;  // 0..1023: one wave per step-row
  int gen = 0;

  __shared__ float c1s[B_BLK];      // 4 KB
  __shared__ float redc[4][4][8];   // wave x d-octet x elem

  for (int b = 0; b < N_BLK; b++) {
    const float* theta = theta_arr + (size_t)b * D_DIM;  // rotated
    float* c0 = c0_arr + (size_t)b * B_BLK;
    float* c1 = c1_arr + (size_t)b * B_BLK;
    float p_k;

    // ---- Phase A: p_k = <x_gw, theta_b> (registers); c0 = f(p)
    {
      const short* xr = xb + (size_t)(b * B_BLK + gw) * D_DIM;
      float s = 0.f;
#pragma unroll
      for (int i = 0; i < 4; i++) {
        int idx = (i * 64 + lane) * 8;
        short8_t xv = *(const short8_t*)(xr + idx);
        float4 t0 = *(const float4*)(theta + idx);
        float4 t1 = *(const float4*)(theta + idx + 4);
        s += bf2f((uint16_t)xv[0]) * t0.x + bf2f((uint16_t)xv[1]) * t0.y +
             bf2f((uint16_t)xv[2]) * t0.z + bf2f((uint16_t)xv[3]) * t0.w +
             bf2f((uint16_t)xv[4]) * t1.x + bf2f((uint16_t)xv[5]) * t1.y +
             bf2f((uint16_t)xv[6]) * t1.z + bf2f((uint16_t)xv[7]) * t1.w;
      }
      s = wave_reduce(s);
      p_k = s;
      if (lane == 0) store_wt(&c0[gw], ETA / (1.f + __expf(s)));
    }
    grid_barrier(flags, release, ++gen, wg, tid);

    // ---- Phase S: c1[k] = f(p_k + tril(G_b)[k,:] . c0)
    {
      int ti = gw >> 7, kr = gw & 127;
      float s = 0.f;
      for (int tj = 0; tj <= ti; tj++) {
        size_t base =
            ((size_t)(b * N_TILE + ti * (ti + 1) / 2 + tj)) * (128 * 128) +
            (size_t)kr * 128;
        uint32_t gv = *(const uint32_t*)(G + base + lane * 2);
        float2 cv = *(const float2*)(c0 + tj * 128 + lane * 2);
        int jc = lane * 2;
        int lim = (tj == ti) ? kr : 128;
        if (jc < lim) s += bf2f(gv & 0xffffu) * cv.x;
        if (jc + 1 < lim) s += bf2f(gv >> 16) * cv.y;
      }
      s = wave_reduce(s);
      if (lane == 0) store_wt(&c1[gw], ETA / (1.f + __expf(p_k + s)));
    }
    grid_barrier(flags, release, ++gen, wg, tid);

    // ---- Phase C: theta_{b+1}[d] = theta_b[d] + sum_k c1[k] xb[k][d]
    // 64 active WGs; WG wg owns d-slice [wg*32, wg*32+32) = one 64B line per
    // row -> coalesced, zero over-fetch, single-writer.
    if (wg < 64) {
#pragma unroll
      for (int i = 0; i < 4; i++) c1s[i * 256 + tid] = c1[i * 256 + tid];
      __syncthreads();
      int d0 = wg * 32;
      const short* xp =
          xb + (size_t)(b * B_BLK) * D_DIM + d0 + (lane & 3) * 8;
      float a8[8] = {0.f, 0.f, 0.f, 0.f, 0.f, 0.f, 0.f, 0.f};
      int rbase = wid * 256 + (lane >> 2);
      for (int i = 0; i < 16; i++) {
        int row = rbase + i * 16;
        short8_t xv = *(const short8_t*)(xp + (size_t)row * D_DIM);
        float c = c1s[row];
#pragma unroll
        for (int jj = 0; jj < 8; jj++) a8[jj] += c * bf2f((uint16_t)xv[jj]);
      }
      // reduce across the 16 lanes sharing (lane&3)
#pragma unroll
      for (int off = 4; off < 64; off <<= 1)
#pragma unroll
        for (int jj = 0; jj < 8; jj++) a8[jj] += __shfl_xor(a8[jj], off, 64);
      if (lane < 4) {
#pragma unroll
        for (int jj = 0; jj < 8; jj++) redc[wid][lane][jj] = a8[jj];
      }
      __syncthreads();
      if (tid < 32) {
        int oct = tid >> 3, e = tid & 7;
        float tot = redc[0][oct][e] + redc[1][oct][e] + redc[2][oct][e] +
                    redc[3][oct][e];
        store_wt(&theta_arr[(size_t)(b + 1) * D_DIM + d0 + tid],
                 theta[d0 + tid] + tot);
      }
    }
    if (b < N_BLK - 1) grid_barrier(flags, release, ++gen, wg, tid);
  }
}

// ---------------------------------------------------------------------------
extern "C" void kernel_launch(void* const* d_in, const int* in_sizes, int n_in,
                              void* d_out, int out_size, void* d_ws,
                              size_t ws_size, hipStream_t stream) {
  const float* theta_in = (const float*)d_in[0];  // (2048,)
  const float* xs = (const float*)d_in[1];        // (16384, 2048) fp32

  char* ws = (char*)d_ws;
  const size_t XB_BYTES = (size_t)N_STEPS * D_DIM * sizeof(short);  // 64MB
  const size_t G_BYTES = (size_t)N_BLK * N_TILE * 128 * 128 * sizeof(short);
  short* xb = (short*)ws;
  short* G = (short*)(ws + XB_BYTES);
  float* theta_arr = (float*)(ws + XB_BYTES + G_BYTES);  // (N_BLK+1) x 2048
  float* c0_arr = theta_arr + (size_t)(N_BLK + 1) * D_DIM;
  float* c1_arr = c0_arr + (size_t)N_BLK * B_BLK;
  int* flags = (int*)(c1_arr + (size_t)N_BLK * B_BLK);
  int* release = flags + NWG * FLAG_STRIDE;

  hipMemsetAsync(flags, 0, (NWG * FLAG_STRIDE + 16) * sizeof(int), stream);
  hipMemcpyAsync(theta_arr, theta_in, D_DIM * sizeof(float),
                 hipMemcpyDeviceToDevice, stream);

  cast_kernel<<<(N_STEPS * D_DIM / 8) / 256, 256, 0, stream>>>(xs, xb);
  gram_kernel<<<N_BLK * N_TILE, 256, 0, stream>>>(xb, G);
  solve_kernel<<<NWG, 256, 0, stream>>>(xb, G, theta_arr, c0_arr, c1_arr,
                                        flags, release);

  hipMemcpyAsync(d_out, theta_arr + (size_t)N_BLK * D_DIM,
                 D_DIM * sizeof(float), hipMemcpyDeviceToDevice, stream);
}

// Round 8
// 445.633 us; speedup vs baseline: 1.0274x; 1.0185x over previous
//
#include <hip/hip_runtime.h>
#include <hip/hip_bf16.h>
#include <stdint.h>

#define D_DIM 2048
#define N_STEPS 16384
#define B_BLK 1024
#define N_BLK (N_STEPS / B_BLK)       // 16
#define T_P (B_BLK / 128)             // 8 tiles per block dim (G layout)
#define N_TILE (T_P * (T_P + 1) / 2)  // 36 lower 128-tiles per block
#define T64 (B_BLK / 64)              // 16 64-tiles per dim
#define N_TILE64 (T64 * (T64 + 1) / 2)  // 136 lower 64-tiles per block
#define ETA 0.01f
#define NWG 256
#define FLAG_STRIDE 16  // ints -> 64B per flag line

typedef __attribute__((ext_vector_type(8))) short short8_t;
typedef __attribute__((ext_vector_type(4))) float floatx4;

__device__ __forceinline__ short f2bf(float f) {
  __hip_bfloat16 h = __float2bfloat16(f);
  return __builtin_bit_cast(short, h);
}
__device__ __forceinline__ float bf2f(uint32_t bits) {
  return __builtin_bit_cast(float, bits << 16);
}

// Write-through store (relaxed agent atomic -> global_store sc0 sc1, no cache
// flush). Visible at MALL once vmcnt retires; __syncthreads drains vmcnt.
__device__ __forceinline__ void store_wt(float* p, float v) {
  __hip_atomic_store(p, v, __ATOMIC_RELAXED, __HIP_MEMORY_SCOPE_AGENT);
}

// Async global->LDS, 16B per lane (lane-linear LDS dest).
__device__ __forceinline__ void gl_lds16(const short* g, short* l) {
  __builtin_amdgcn_global_load_lds(
      (const __attribute__((address_space(1))) void*)g,
      (__attribute__((address_space(3))) void*)l, 16, 0, 0);
}

// ---------------------------------------------------------------------------
// Phase 0: cast xs (fp32) -> xb (bf16), one pass.
// ---------------------------------------------------------------------------
__global__ __launch_bounds__(256) void cast_kernel(const float* __restrict__ xs,
                                                   short* __restrict__ xb) {
  size_t i = (size_t)blockIdx.x * 256 + threadIdx.x;
  float4 a = ((const float4*)xs)[i * 2];
  float4 b = ((const float4*)xs)[i * 2 + 1];
  short8_t v;
  v[0] = f2bf(a.x); v[1] = f2bf(a.y); v[2] = f2bf(a.z); v[3] = f2bf(a.w);
  v[4] = f2bf(b.x); v[5] = f2bf(b.y); v[6] = f2bf(b.z); v[7] = f2bf(b.w);
  *(short8_t*)(xb + i * 8) = v;
}

// ---------------------------------------------------------------------------
// Phase 1 (R8): Gram via 64x64 tiles -> 2176 WGs (~8/CU resident; 16 KB LDS,
// 16 acc VGPRs). R4-R7 showed gram is latency-serialized at 2.25 WGs/CU with
// every pipe <15% busy; this quadruples wave-level overlap (m114 mechanism).
// Results are written into the SAME packed 128-tile G layout (diag 128-tiles'
// upper 64-subtile is never read by Phase S and is simply not computed), and
// the K-accumulation order is identical -> G is bitwise identical to R7.
// ---------------------------------------------------------------------------
__global__ __launch_bounds__(256) void gram_kernel(const short* __restrict__ xb,
                                                   short* __restrict__ G) {
  int i = blockIdx.x;
  int x = i & 7, j = i >> 3;  // x: XCD slot (blockIdx%8 heuristic), j: 0..271
  int b = (j < N_TILE64) ? x : x + 8;
  int t = (j < N_TILE64) ? j : j - N_TILE64;
  int TI = 0;
  while ((TI + 1) * (TI + 2) / 2 <= t) TI++;
  int TJ = t - TI * (TI + 1) / 2;

  __shared__ short As[64 * 64];  // 8 KB
  __shared__ short Bs[64 * 64];  // 8 KB

  int tid = threadIdx.x;
  int lane = tid & 63;
  int w = tid >> 6;
  int wm = w >> 1, wn = w & 1;  // wave -> 32x32 quadrant
  int quad = lane >> 4, rr = lane & 15;

  floatx4 acc[2][2];
#pragma unroll
  for (int ii = 0; ii < 2; ii++)
#pragma unroll
    for (int jj = 0; jj < 2; jj++)
#pragma unroll
      for (int r = 0; r < 4; r++) acc[ii][jj][r] = 0.f;

  const short* Arow = xb + (size_t)(b * B_BLK + TI * 64) * D_DIM;
  const short* Brow = xb + (size_t)(b * B_BLK + TJ * 64) * D_DIM;
  bool diag = (TI == TJ);

  for (int kk = 0; kk < D_DIM; kk += 64) {
    // stage 64 rows x 64 cols bf16 = 8 KB = 512 chunks of 16B; 2 per thread
#pragma unroll
    for (int c = 0; c < 2; c++) {
      int chunk = c * 256 + tid;
      int row = chunk >> 3, slot = chunk & 7;
      int cc = slot ^ (row & 7);  // XOR column swizzle
      gl_lds16(Arow + (size_t)row * D_DIM + kk + cc * 8, &As[chunk * 8]);
      if (!diag)
        gl_lds16(Brow + (size_t)row * D_DIM + kk + cc * 8, &Bs[chunk * 8]);
    }
    __syncthreads();  // vmcnt(0): staging complete

    const short* Bsrc = diag ? As : Bs;
#pragma unroll
    for (int ks = 0; ks < 2; ks++) {  // k-offsets 0, 32
      short8_t af[2], bfr[2];
#pragma unroll
      for (int mt = 0; mt < 2; mt++) {
        int r = wm * 32 + mt * 16 + rr;
        int slot = (ks * 4 + quad) ^ (r & 7);
        af[mt] = *(const short8_t*)(&As[r * 64 + slot * 8]);
      }
#pragma unroll
      for (int nt = 0; nt < 2; nt++) {
        int r = wn * 32 + nt * 16 + rr;
        int slot = (ks * 4 + quad) ^ (r & 7);
        bfr[nt] = *(const short8_t*)(&Bsrc[r * 64 + slot * 8]);
      }
#pragma unroll
      for (int mt = 0; mt < 2; mt++)
#pragma unroll
        for (int nt = 0; nt < 2; nt++)
          acc[mt][nt] = __builtin_amdgcn_mfma_f32_16x16x32_bf16(
              af[mt], bfr[nt], acc[mt][nt], 0, 0, 0);
    }
    __syncthreads();
  }

  // Write into packed 128-tile layout. C/D: col=lane&15, row=(lane>>4)*4+reg.
  int ti128 = TI >> 1, tj128 = TJ >> 1;
  size_t gbase =
      ((size_t)(b * N_TILE + ti128 * (ti128 + 1) / 2 + tj128)) * (128 * 128);
  int col0 = lane & 15;
  int row0 = (lane >> 4) * 4;
#pragma unroll
  for (int mt = 0; mt < 2; mt++)
#pragma unroll
    for (int nt = 0; nt < 2; nt++)
#pragma unroll
      for (int r = 0; r < 4; r++) {
        int row = (TI & 1) * 64 + wm * 32 + mt * 16 + row0 + r;
        int col = (TJ & 1) * 64 + wn * 32 + nt * 16 + col0;
        G[gbase + (size_t)row * 128 + col] = f2bf(acc[mt][nt][r]);
      }
}

// ---------------------------------------------------------------------------
// Flush-free grid barrier (relaxed agent atomics only; see R3 notes).
// ---------------------------------------------------------------------------
__device__ __forceinline__ void grid_barrier(int* flags, int* release, int gen,
                                             int wg, int tid) {
  __syncthreads();
  if (wg == 0) {
    if (tid > 0) {
      int guard = 0;
      while (__hip_atomic_load(&flags[tid * FLAG_STRIDE], __ATOMIC_RELAXED,
                               __HIP_MEMORY_SCOPE_AGENT) < gen &&
             guard < (1 << 20)) {
        guard++;
        __builtin_amdgcn_s_sleep(1);
      }
    }
    __syncthreads();
    if (tid == 0)
      __hip_atomic_store(release, gen, __ATOMIC_RELAXED,
                         __HIP_MEMORY_SCOPE_AGENT);
  } else {
    if (tid == 0) {
      __hip_atomic_store(&flags[wg * FLAG_STRIDE], gen, __ATOMIC_RELAXED,
                         __HIP_MEMORY_SCOPE_AGENT);
      int guard = 0;
      while (__hip_atomic_load(release, __ATOMIC_RELAXED,
                               __HIP_MEMORY_SCOPE_AGENT) < gen &&
             guard < (1 << 20)) {
        guard++;
        __builtin_amdgcn_s_sleep(1);
      }
    }
  }
  asm volatile("" ::: "memory");
  __syncthreads();
}

__device__ __forceinline__ float wave_reduce(float s) {
  for (int off = 32; off; off >>= 1) s += __shfl_xor(s, off, 64);
  return s;
}

// ---------------------------------------------------------------------------
// Phase 2: sequential over blocks, 3 flush-free barriers per block.
// (frozen since R4)
// ---------------------------------------------------------------------------
__global__ __launch_bounds__(256, 1) void solve_kernel(
    const short* __restrict__ xb, const short* __restrict__ G,
    float* __restrict__ theta_arr, float* __restrict__ c0_arr,
    float* __restrict__ c1_arr, int* flags, int* release) {
  int tid = threadIdx.x;
  int wg = blockIdx.x;
  int lane = tid & 63;
  int wid = tid >> 6;
  int gw = wg * 4 + wid;  // 0..1023: one wave per step-row
  int gen = 0;

  __shared__ float c1s[B_BLK];      // 4 KB
  __shared__ float redc[4][4][8];   // wave x d-octet x elem

  for (int b = 0; b < N_BLK; b++) {
    const float* theta = theta_arr + (size_t)b * D_DIM;  // rotated
    float* c0 = c0_arr + (size_t)b * B_BLK;
    float* c1 = c1_arr + (size_t)b * B_BLK;
    float p_k;

    // ---- Phase A: p_k = <x_gw, theta_b> (registers); c0 = f(p)
    {
      const short* xr = xb + (size_t)(b * B_BLK + gw) * D_DIM;
      float s = 0.f;
#pragma unroll
      for (int i = 0; i < 4; i++) {
        int idx = (i * 64 + lane) * 8;
        short8_t xv = *(const short8_t*)(xr + idx);
        float4 t0 = *(const float4*)(theta + idx);
        float4 t1 = *(const float4*)(theta + idx + 4);
        s += bf2f((uint16_t)xv[0]) * t0.x + bf2f((uint16_t)xv[1]) * t0.y +
             bf2f((uint16_t)xv[2]) * t0.z + bf2f((uint16_t)xv[3]) * t0.w +
             bf2f((uint16_t)xv[4]) * t1.x + bf2f((uint16_t)xv[5]) * t1.y +
             bf2f((uint16_t)xv[6]) * t1.z + bf2f((uint16_t)xv[7]) * t1.w;
      }
      s = wave_reduce(s);
      p_k = s;
      if (lane == 0) store_wt(&c0[gw], ETA / (1.f + __expf(s)));
    }
    grid_barrier(flags, release, ++gen, wg, tid);

    // ---- Phase S: c1[k] = f(p_k + tril(G_b)[k,:] . c0)
    {
      int ti = gw >> 7, kr = gw & 127;
      float s = 0.f;
      for (int tj = 0; tj <= ti; tj++) {
        size_t base =
            ((size_t)(b * N_TILE + ti * (ti + 1) / 2 + tj)) * (128 * 128) +
            (size_t)kr * 128;
        uint32_t gv = *(const uint32_t*)(G + base + lane * 2);
        float2 cv = *(const float2*)(c0 + tj * 128 + lane * 2);
        int jc = lane * 2;
        int lim = (tj == ti) ? kr : 128;
        if (jc < lim) s += bf2f(gv & 0xffffu) * cv.x;
        if (jc + 1 < lim) s += bf2f(gv >> 16) * cv.y;
      }
      s = wave_reduce(s);
      if (lane == 0) store_wt(&c1[gw], ETA / (1.f + __expf(p_k + s)));
    }
    grid_barrier(flags, release, ++gen, wg, tid);

    // ---- Phase C: theta_{b+1}[d] = theta_b[d] + sum_k c1[k] xb[k][d]
    // 64 active WGs; WG wg owns d-slice [wg*32, wg*32+32) = one 64B line per
    // row -> coalesced, zero over-fetch, single-writer.
    if (wg < 64) {
#pragma unroll
      for (int i = 0; i < 4; i++) c1s[i * 256 + tid] = c1[i * 256 + tid];
      __syncthreads();
      int d0 = wg * 32;
      const short* xp =
          xb + (size_t)(b * B_BLK) * D_DIM + d0 + (lane & 3) * 8;
      float a8[8] = {0.f, 0.f, 0.f, 0.f, 0.f, 0.f, 0.f, 0.f};
      int rbase = wid * 256 + (lane >> 2);
      for (int i = 0; i < 16; i++) {
        int row = rbase + i * 16;
        short8_t xv = *(const short8_t*)(xp + (size_t)row * D_DIM);
        float c = c1s[row];
#pragma unroll
        for (int jj = 0; jj < 8; jj++) a8[jj] += c * bf2f((uint16_t)xv[jj]);
      }
      // reduce across the 16 lanes sharing (lane&3)
#pragma unroll
      for (int off = 4; off < 64; off <<= 1)
#pragma unroll
        for (int jj = 0; jj < 8; jj++) a8[jj] += __shfl_xor(a8[jj], off, 64);
      if (lane < 4) {
#pragma unroll
        for (int jj = 0; jj < 8; jj++) redc[wid][lane][jj] = a8[jj];
      }
      __syncthreads();
      if (tid < 32) {
        int oct = tid >> 3, e = tid & 7;
        float tot = redc[0][oct][e] + redc[1][oct][e] + redc[2][oct][e] +
                    redc[3][oct][e];
        store_wt(&theta_arr[(size_t)(b + 1) * D_DIM + d0 + tid],
                 theta[d0 + tid] + tot);
      }
    }
    if (b < N_BLK - 1) grid_barrier(flags, release, ++gen, wg, tid);
  }
}

// ---------------------------------------------------------------------------
extern "C" void kernel_launch(void* const* d_in, const int* in_sizes, int n_in,
                              void* d_out, int out_size, void* d_ws,
                              size_t ws_size, hipStream_t stream) {
  const float* theta_in = (const float*)d_in[0];  // (2048,)
  const float* xs = (const float*)d_in[1];        // (16384, 2048) fp32

  char* ws = (char*)d_ws;
  const size_t XB_BYTES = (size_t)N_STEPS * D_DIM * sizeof(short);  // 64MB
  const size_t G_BYTES = (size_t)N_BLK * N_TILE * 128 * 128 * sizeof(short);
  short* xb = (short*)ws;
  short* G = (short*)(ws + XB_BYTES);
  float* theta_arr = (float*)(ws + XB_BYTES + G_BYTES);  // (N_BLK+1) x 2048
  float* c0_arr = theta_arr + (size_t)(N_BLK + 1) * D_DIM;
  float* c1_arr = c0_arr + (size_t)N_BLK * B_BLK;
  int* flags = (int*)(c1_arr + (size_t)N_BLK * B_BLK);
  int* release = flags + NWG * FLAG_STRIDE;

  hipMemsetAsync(flags, 0, (NWG * FLAG_STRIDE + 16) * sizeof(int), stream);
  hipMemcpyAsync(theta_arr, theta_in, D_DIM * sizeof(float),
                 hipMemcpyDeviceToDevice, stream);

  cast_kernel<<<(N_STEPS * D_DIM / 8) / 256, 256, 0, stream>>>(xs, xb);
  gram_kernel<<<N_BLK * N_TILE64, 256, 0, stream>>>(xb, G);  // 2176 WGs
  solve_kernel<<<NWG, 256, 0, stream>>>(xb, G, theta_arr, c0_arr, c1_arr,
                                        flags, release);

  hipMemcpyAsync(d_out, theta_arr + (size_t)N_BLK * D_DIM,
                 D_DIM * sizeof(float), hipMemcpyDeviceToDevice, stream);
}